// Round 18
// baseline (66.088 us; speedup 1.0000x reference)
//
#include <hip/hip_runtime.h>
#include <math.h>

// Problem: B=64, T=512, D=1024.
//   v[b,d]     = sum_e W[d,e] * x[b,T-1,e]
//   scores[b,t]= sum_d x[b,t,d] * v[b,d]          (t in 0..510)
//   alpha      = softmax_t(scores)
//   c[b,d]     = sum_t alpha[b,t] * x[b,t,d]
//   out[b]     = concat(c[b,:], x[b,T-1,:])       (64 x 2048 fp32)
//
// HISTORY:
//  R4  flash G16 prefetch, paired rows           49.3 us
//  R5-R9 fused finalize w/ __threadfence         ~200 us (L2 wb/inv -> dead end)
//  R10 flash G32 lb(256,4)                       52.0 us
//  R11 two-pass (x read twice)                   68.1 us (+16us = 2nd pass BW)
//  R12 k_v 4x parallel + k_chunk lb(256,6) TLP   41.3 us  <- best
//  R13-R15 k_chunk inner-loop variants           42.7-44.8 us (chain exonerated)
//  R16 k_chunk x2:  dur 63.8 => k_chunk+gap = 22.5us; k_chunk at ~97% of the
//      HBM floor (x evicted from L3 each replay by 512MB poison fills).
//      Residual 18.8us = k_v + k_final + 2*gap + fixed-graph-overhead.
//  R17: INSTRUMENTATION 2 — k_v x4 (idempotent). dur = 41.3 + 3*(k_v+gap).
//      ~47-50 -> gaps cheap, residual is fixed overhead -> near-roofline.
//      ~58-62 -> gap ~6us -> dispatch-count reduction is the next lever.

#define BB 64
#define TT 512
#define DD 1024
#define TH 511           // valid history rows: 0..510
#define GROUPS 32        // blocks per batch
#define RPW 4            // rows per wave (4 waves * 4 = 16 rows per block)

// workspace (floats):
//   v      : [BB][DD]          off 0            (65536)
//   partC  : [BB][GROUPS][DD]  off 65536        (2097152, 8 MB)
//   partML : [BB][GROUPS][2]   off 2162688      (4096)

// ---------------- kernel 1: v = x_last @ W^T -------------------------------
// 1024 blocks x 4 waves; wave = 4 d-rows (W stationary) x 4 batches.
__global__ __launch_bounds__(256, 4) void k_v(const float* __restrict__ x,
                                              const float* __restrict__ W,
                                              float* __restrict__ v) {
    const int wave = threadIdx.x >> 6;
    const int lane = threadIdx.x & 63;
    const int wg   = blockIdx.x * 4 + wave;   // 0..4095
    const int d0   = (wg >> 4) * 4;           // 256 d-quads
    const int bg   = wg & 15;                 // 16 batch-groups of 4

    float4 w4[4][4];
#pragma unroll
    for (int k = 0; k < 4; ++k)
#pragma unroll
        for (int j = 0; j < 4; ++j)
            w4[k][j] = *(const float4*)(W + (size_t)(d0 + k) * DD + j * 256 + lane * 4);

    float res = 0.f;                          // lanes 0..15: (b=bg*4+(l>>2), d=d0+(l&3))
#pragma unroll
    for (int i = 0; i < 4; ++i) {
        const int b = bg * 4 + i;
        const float* xl = x + ((size_t)b * TT + (TT - 1)) * DD;
        float4 x4[4];
#pragma unroll
        for (int j = 0; j < 4; ++j)
            x4[j] = *(const float4*)(xl + j * 256 + lane * 4);
        float p[4];
#pragma unroll
        for (int k = 0; k < 4; ++k)
            p[k] = w4[k][0].x * x4[0].x + w4[k][0].y * x4[0].y + w4[k][0].z * x4[0].z + w4[k][0].w * x4[0].w
                 + w4[k][1].x * x4[1].x + w4[k][1].y * x4[1].y + w4[k][1].z * x4[1].z + w4[k][1].w * x4[1].w
                 + w4[k][2].x * x4[2].x + w4[k][2].y * x4[2].y + w4[k][2].z * x4[2].z + w4[k][2].w * x4[2].w
                 + w4[k][3].x * x4[3].x + w4[k][3].y * x4[3].y + w4[k][3].z * x4[3].z + w4[k][3].w * x4[3].w;
#pragma unroll
        for (int mm = 1; mm < 64; mm <<= 1) {
#pragma unroll
            for (int k = 0; k < 4; ++k) p[k] += __shfl_xor(p[k], mm, 64);
        }
#pragma unroll
        for (int k = 0; k < 4; ++k)
            if (lane == i * 4 + k) res = p[k];
    }
    if (lane < 16)
        v[(size_t)(bg * 4 + (lane >> 2)) * DD + d0 + (lane & 3)] = res;
}

// ---------------- kernel 2: minimal-register flash chunk (R12 exact) -------
__global__ __launch_bounds__(256, 6) void k_chunk(const float* __restrict__ x,
                                                  const float* __restrict__ v,
                                                  float* __restrict__ partC,
                                                  float* __restrict__ partML) {
    __shared__ float cw[4][DD];               // 16 KB combine buffer
    __shared__ float cml[4][2];

    const int b    = blockIdx.x >> 5;         // / GROUPS
    const int g    = blockIdx.x & (GROUPS - 1);
    const int wave = threadIdx.x >> 6;
    const int lane = threadIdx.x & 63;
    const int r0   = g * 16 + wave * RPW;     // <= 508
    const int col  = lane * 4;

    const float* xb = x + (size_t)b * TT * DD;
    const float* vb = v + (size_t)b * DD + col;
    const float4 vv0 = *(const float4*)(vb);
    const float4 vv1 = *(const float4*)(vb + 256);
    const float4 vv2 = *(const float4*)(vb + 512);
    const float4 vv3 = *(const float4*)(vb + 768);

    float m = -INFINITY, l = 0.f;
    float4 acc0 = make_float4(0,0,0,0), acc1 = make_float4(0,0,0,0);
    float4 acc2 = make_float4(0,0,0,0), acc3 = make_float4(0,0,0,0);

#pragma unroll
    for (int i = 0; i < RPW; ++i) {
        const int r  = r0 + i;
        const int rc = min(r, TH - 1);        // clamped addr; masked via score
        const float* p = xb + (size_t)rc * DD + col;
        const float4 x0 = *(const float4*)(p);
        const float4 x1 = *(const float4*)(p + 256);
        const float4 x2 = *(const float4*)(p + 512);
        const float4 x3 = *(const float4*)(p + 768);

        float s = vv0.x * x0.x + vv0.y * x0.y + vv0.z * x0.z + vv0.w * x0.w
                + vv1.x * x1.x + vv1.y * x1.y + vv1.z * x1.z + vv1.w * x1.w
                + vv2.x * x2.x + vv2.y * x2.y + vv2.z * x2.z + vv2.w * x2.w
                + vv3.x * x3.x + vv3.y * x3.y + vv3.z * x3.z + vv3.w * x3.w;
#pragma unroll
        for (int mm = 1; mm < 64; mm <<= 1) s += __shfl_xor(s, mm, 64);
        if (r >= TH) s = -INFINITY;           // invalid tail row -> e = 0

        const float mnew = fmaxf(m, s);
        if (mnew > m) {                        // wave-uniform branch
            const float sc = __expf(m - mnew); // first iter: exp(-inf)=0
            acc0.x *= sc; acc0.y *= sc; acc0.z *= sc; acc0.w *= sc;
            acc1.x *= sc; acc1.y *= sc; acc1.z *= sc; acc1.w *= sc;
            acc2.x *= sc; acc2.y *= sc; acc2.z *= sc; acc2.w *= sc;
            acc3.x *= sc; acc3.y *= sc; acc3.z *= sc; acc3.w *= sc;
            l *= sc; m = mnew;
        }
        const float e = __expf(s - m);
        l += e;
        acc0.x += e * x0.x; acc0.y += e * x0.y; acc0.z += e * x0.z; acc0.w += e * x0.w;
        acc1.x += e * x1.x; acc1.y += e * x1.y; acc1.z += e * x1.z; acc1.w += e * x1.w;
        acc2.x += e * x2.x; acc2.y += e * x2.y; acc2.z += e * x2.z; acc2.w += e * x2.w;
        acc3.x += e * x3.x; acc3.y += e * x3.y; acc3.z += e * x3.z; acc3.w += e * x3.w;
    }

    // one cross-wave combine per block
    *(float4*)(&cw[wave][0 * 256 + col]) = acc0;
    *(float4*)(&cw[wave][1 * 256 + col]) = acc1;
    *(float4*)(&cw[wave][2 * 256 + col]) = acc2;
    *(float4*)(&cw[wave][3 * 256 + col]) = acc3;
    if (lane == 0) { cml[wave][0] = m; cml[wave][1] = l; }
    __syncthreads();

    const float M = fmaxf(fmaxf(cml[0][0], cml[1][0]), fmaxf(cml[2][0], cml[3][0]));
    const float w0 = __expf(cml[0][0] - M), w1 = __expf(cml[1][0] - M);
    const float w2 = __expf(cml[2][0] - M), w3 = __expf(cml[3][0] - M);
    const float L = w0 * cml[0][1] + w1 * cml[1][1] + w2 * cml[2][1] + w3 * cml[3][1];

    const int d0 = threadIdx.x * 4;
    const float4 s0 = *(const float4*)(&cw[0][d0]);
    const float4 s1 = *(const float4*)(&cw[1][d0]);
    const float4 s2 = *(const float4*)(&cw[2][d0]);
    const float4 s3 = *(const float4*)(&cw[3][d0]);
    float4 o;
    o.x = w0 * s0.x + w1 * s1.x + w2 * s2.x + w3 * s3.x;
    o.y = w0 * s0.y + w1 * s1.y + w2 * s2.y + w3 * s3.y;
    o.z = w0 * s0.z + w1 * s1.z + w2 * s2.z + w3 * s3.z;
    o.w = w0 * s0.w + w1 * s1.w + w2 * s2.w + w3 * s3.w;
    *(float4*)(partC + ((size_t)b * GROUPS + g) * DD + d0) = o;
    if (threadIdx.x == 0) {
        partML[((size_t)b * GROUPS + g) * 2 + 0] = M;
        partML[((size_t)b * GROUPS + g) * 2 + 1] = L;
    }
}

// ---------------- kernel 3: combine partials, divide, append x_last --------
__global__ __launch_bounds__(256) void k_final(const float* __restrict__ x,
                                               const float* __restrict__ partC,
                                               const float* __restrict__ partML,
                                               float* __restrict__ out) {
    const int b = blockIdx.x >> 2;
    const int q = blockIdx.x & 3;
    __shared__ float wgt[GROUPS];
    __shared__ float lsh;

    if (threadIdx.x < GROUPS) {
        float M = -INFINITY;
        for (int cc = 0; cc < GROUPS; ++cc)
            M = fmaxf(M, partML[((size_t)b * GROUPS + cc) * 2]);
        wgt[threadIdx.x] = __expf(partML[((size_t)b * GROUPS + threadIdx.x) * 2] - M);
    }
    __syncthreads();
    if (threadIdx.x == 0) {
        float L = 0.f;
        for (int cc = 0; cc < GROUPS; ++cc)
            L += partML[((size_t)b * GROUPS + cc) * 2 + 1] * wgt[cc];
        lsh = 1.f / L;
    }
    __syncthreads();
    const float invL = lsh;

    const int d = q * 256 + threadIdx.x;
    float acc = 0.f;
#pragma unroll 8
    for (int cc = 0; cc < GROUPS; ++cc)
        acc += wgt[cc] * partC[((size_t)b * GROUPS + cc) * DD + d];
    out[(size_t)b * 2048 + d] = acc * invL;
    out[(size_t)b * 2048 + 1024 + d] = x[((size_t)b * TT + (TT - 1)) * DD + d];
}

extern "C" void kernel_launch(void* const* d_in, const int* in_sizes, int n_in,
                              void* d_out, int out_size, void* d_ws, size_t ws_size,
                              hipStream_t stream) {
    const float* x = (const float*)d_in[0];   // (64,512,1024) fp32
    const float* W = (const float*)d_in[1];   // (1024,1024) fp32
    float* out = (float*)d_out;               // (64,2048) fp32

    float* ws     = (float*)d_ws;             // ~8.5 MB
    float* v      = ws;                                           // 65536
    float* partC  = ws + 65536;                                   // 2097152
    float* partML = ws + 65536 + (size_t)BB * GROUPS * DD;        // 4096

    // INSTRUMENTATION: k_v x4 (idempotent). dur = 41.3 + 3*(k_v + gap).
    k_v<<<1024, 256, 0, stream>>>(x, W, v);
    k_v<<<1024, 256, 0, stream>>>(x, W, v);
    k_v<<<1024, 256, 0, stream>>>(x, W, v);
    k_v<<<1024, 256, 0, stream>>>(x, W, v);
    k_chunk<<<BB * GROUPS, 256, 0, stream>>>(x, v, partC, partML);
    k_final<<<BB * 4, 256, 0, stream>>>(x, partC, partML, out);
}

// Round 19
// 41.591 us; speedup vs baseline: 1.5890x; 1.5890x over previous
//
#include <hip/hip_runtime.h>
#include <math.h>

// Problem: B=64, T=512, D=1024.
//   v[b,d]     = sum_e W[d,e] * x[b,T-1,e]
//   scores[b,t]= sum_d x[b,t,d] * v[b,d]          (t in 0..510)
//   alpha      = softmax_t(scores)
//   c[b,d]     = sum_t alpha[b,t] * x[b,t,d]
//   out[b]     = concat(c[b,:], x[b,T-1,:])       (64 x 2048 fp32)
//
// HISTORY:
//  R4  flash G16 prefetch, paired rows           49.3 us
//  R5-R9 fused finalize w/ __threadfence         ~200 us (L2 wb/inv per block -> dead end;
//        also rules out cooperative grid.sync fusion: same per-block fence cost)
//  R10 flash G32 lb(256,4)                       52.0 us
//  R11 two-pass (x read twice)                   68.1 us
//  R12 k_v 4x parallel + k_chunk lb(256,6) TLP   41.3 us  <- best
//  R13-R15 k_chunk inner variants                42.7-44.8 us (inner chain exonerated)
//  R16 k_chunk x2: k_chunk+gap = 22.5us (x L3-evicted by poison fills each replay)
//  R17 k_v x4:     k_v+gap    =  8.3us
//      Two readings: (A) gap~0.5 -> k_v really ~8us (128MB redundant L2 traffic);
//                    (B) gap~6  -> dispatch gaps are 18us of the 41.3.
//  R18: k_v traffic diet (W re-read 64->32MB, 8 batches/wave, pair-ILP) +
//       vectorized k_final. Reading A -> ~36-38us; Reading B -> ~41 (neutral).

#define BB 64
#define TT 512
#define DD 1024
#define TH 511           // valid history rows: 0..510
#define GROUPS 32        // blocks per batch
#define RPW 4            // rows per wave (4 waves * 4 = 16 rows per block)

// workspace (floats):
//   v      : [BB][DD]          off 0            (65536)
//   partC  : [BB][GROUPS][DD]  off 65536        (2097152, 8 MB)
//   partML : [BB][GROUPS][2]   off 2162688      (4096)

// ---------------- kernel 1: v = x_last @ W^T -------------------------------
// 512 blocks x 4 waves = 2048 waves: (256 d-quads) x (8 batch-groups of 8).
// W stationary (64 VGPR); 8 batches per wave in PAIRS -> 8 parallel butterfly
// chains per pair-step. W re-read total 32MB (was 64MB), x_last 64MB (L2).
// All dots inline — passing local arrays to a helper demotes them to scratch.
__global__ __launch_bounds__(256, 4) void k_v(const float* __restrict__ x,
                                              const float* __restrict__ W,
                                              float* __restrict__ v) {
    const int wave = threadIdx.x >> 6;
    const int lane = threadIdx.x & 63;
    const int wg   = blockIdx.x * 4 + wave;   // 0..2047
    const int d0   = (wg >> 3) * 4;           // 256 d-quads
    const int bg   = wg & 7;                  // 8 batch-groups of 8

    float4 w4[4][4];
#pragma unroll
    for (int k = 0; k < 4; ++k)
#pragma unroll
        for (int j = 0; j < 4; ++j)
            w4[k][j] = *(const float4*)(W + (size_t)(d0 + k) * DD + j * 256 + lane * 4);

    float res = 0.f;                          // lanes 0..31: (b=bg*8+(l>>2), d=d0+(l&3))
#pragma unroll
    for (int ip = 0; ip < 4; ++ip) {
        const int i0 = ip * 2;
        const float* xl0 = x + ((size_t)(bg * 8 + i0) * TT + (TT - 1)) * DD;
        const float* xl1 = xl0 + (size_t)TT * DD;
        float4 xA[4], xB[4];
#pragma unroll
        for (int j = 0; j < 4; ++j) {
            xA[j] = *(const float4*)(xl0 + j * 256 + lane * 4);
            xB[j] = *(const float4*)(xl1 + j * 256 + lane * 4);
        }
        float pA[4], pB[4];
#pragma unroll
        for (int k = 0; k < 4; ++k) {
            pA[k] = w4[k][0].x*xA[0].x + w4[k][0].y*xA[0].y + w4[k][0].z*xA[0].z + w4[k][0].w*xA[0].w
                  + w4[k][1].x*xA[1].x + w4[k][1].y*xA[1].y + w4[k][1].z*xA[1].z + w4[k][1].w*xA[1].w
                  + w4[k][2].x*xA[2].x + w4[k][2].y*xA[2].y + w4[k][2].z*xA[2].z + w4[k][2].w*xA[2].w
                  + w4[k][3].x*xA[3].x + w4[k][3].y*xA[3].y + w4[k][3].z*xA[3].z + w4[k][3].w*xA[3].w;
            pB[k] = w4[k][0].x*xB[0].x + w4[k][0].y*xB[0].y + w4[k][0].z*xB[0].z + w4[k][0].w*xB[0].w
                  + w4[k][1].x*xB[1].x + w4[k][1].y*xB[1].y + w4[k][1].z*xB[1].z + w4[k][1].w*xB[1].w
                  + w4[k][2].x*xB[2].x + w4[k][2].y*xB[2].y + w4[k][2].z*xB[2].z + w4[k][2].w*xB[2].w
                  + w4[k][3].x*xB[3].x + w4[k][3].y*xB[3].y + w4[k][3].z*xB[3].z + w4[k][3].w*xB[3].w;
        }
#pragma unroll
        for (int mm = 1; mm < 64; mm <<= 1) {  // 8 independent butterfly chains
#pragma unroll
            for (int k = 0; k < 4; ++k) {
                pA[k] += __shfl_xor(pA[k], mm, 64);
                pB[k] += __shfl_xor(pB[k], mm, 64);
            }
        }
#pragma unroll
        for (int k = 0; k < 4; ++k) {
            if (lane == i0 * 4 + k)       res = pA[k];
            if (lane == (i0 + 1) * 4 + k) res = pB[k];
        }
    }
    if (lane < 32)
        v[(size_t)(bg * 8 + (lane >> 2)) * DD + d0 + (lane & 3)] = res;
}

// ---------------- kernel 2: minimal-register flash chunk (R12 exact) -------
__global__ __launch_bounds__(256, 6) void k_chunk(const float* __restrict__ x,
                                                  const float* __restrict__ v,
                                                  float* __restrict__ partC,
                                                  float* __restrict__ partML) {
    __shared__ float cw[4][DD];               // 16 KB combine buffer
    __shared__ float cml[4][2];

    const int b    = blockIdx.x >> 5;         // / GROUPS
    const int g    = blockIdx.x & (GROUPS - 1);
    const int wave = threadIdx.x >> 6;
    const int lane = threadIdx.x & 63;
    const int r0   = g * 16 + wave * RPW;     // <= 508
    const int col  = lane * 4;

    const float* xb = x + (size_t)b * TT * DD;
    const float* vb = v + (size_t)b * DD + col;
    const float4 vv0 = *(const float4*)(vb);
    const float4 vv1 = *(const float4*)(vb + 256);
    const float4 vv2 = *(const float4*)(vb + 512);
    const float4 vv3 = *(const float4*)(vb + 768);

    float m = -INFINITY, l = 0.f;
    float4 acc0 = make_float4(0,0,0,0), acc1 = make_float4(0,0,0,0);
    float4 acc2 = make_float4(0,0,0,0), acc3 = make_float4(0,0,0,0);

#pragma unroll
    for (int i = 0; i < RPW; ++i) {
        const int r  = r0 + i;
        const int rc = min(r, TH - 1);        // clamped addr; masked via score
        const float* p = xb + (size_t)rc * DD + col;
        const float4 x0 = *(const float4*)(p);
        const float4 x1 = *(const float4*)(p + 256);
        const float4 x2 = *(const float4*)(p + 512);
        const float4 x3 = *(const float4*)(p + 768);

        float s = vv0.x * x0.x + vv0.y * x0.y + vv0.z * x0.z + vv0.w * x0.w
                + vv1.x * x1.x + vv1.y * x1.y + vv1.z * x1.z + vv1.w * x1.w
                + vv2.x * x2.x + vv2.y * x2.y + vv2.z * x2.z + vv2.w * x2.w
                + vv3.x * x3.x + vv3.y * x3.y + vv3.z * x3.z + vv3.w * x3.w;
#pragma unroll
        for (int mm = 1; mm < 64; mm <<= 1) s += __shfl_xor(s, mm, 64);
        if (r >= TH) s = -INFINITY;           // invalid tail row -> e = 0

        const float mnew = fmaxf(m, s);
        if (mnew > m) {                        // wave-uniform branch
            const float sc = __expf(m - mnew); // first iter: exp(-inf)=0
            acc0.x *= sc; acc0.y *= sc; acc0.z *= sc; acc0.w *= sc;
            acc1.x *= sc; acc1.y *= sc; acc1.z *= sc; acc1.w *= sc;
            acc2.x *= sc; acc2.y *= sc; acc2.z *= sc; acc2.w *= sc;
            acc3.x *= sc; acc3.y *= sc; acc3.z *= sc; acc3.w *= sc;
            l *= sc; m = mnew;
        }
        const float e = __expf(s - m);
        l += e;
        acc0.x += e * x0.x; acc0.y += e * x0.y; acc0.z += e * x0.z; acc0.w += e * x0.w;
        acc1.x += e * x1.x; acc1.y += e * x1.y; acc1.z += e * x1.z; acc1.w += e * x1.w;
        acc2.x += e * x2.x; acc2.y += e * x2.y; acc2.z += e * x2.z; acc2.w += e * x2.w;
        acc3.x += e * x3.x; acc3.y += e * x3.y; acc3.z += e * x3.z; acc3.w += e * x3.w;
    }

    // one cross-wave combine per block
    *(float4*)(&cw[wave][0 * 256 + col]) = acc0;
    *(float4*)(&cw[wave][1 * 256 + col]) = acc1;
    *(float4*)(&cw[wave][2 * 256 + col]) = acc2;
    *(float4*)(&cw[wave][3 * 256 + col]) = acc3;
    if (lane == 0) { cml[wave][0] = m; cml[wave][1] = l; }
    __syncthreads();

    const float M = fmaxf(fmaxf(cml[0][0], cml[1][0]), fmaxf(cml[2][0], cml[3][0]));
    const float w0 = __expf(cml[0][0] - M), w1 = __expf(cml[1][0] - M);
    const float w2 = __expf(cml[2][0] - M), w3 = __expf(cml[3][0] - M);
    const float L = w0 * cml[0][1] + w1 * cml[1][1] + w2 * cml[2][1] + w3 * cml[3][1];

    const int d0 = threadIdx.x * 4;
    const float4 s0 = *(const float4*)(&cw[0][d0]);
    const float4 s1 = *(const float4*)(&cw[1][d0]);
    const float4 s2 = *(const float4*)(&cw[2][d0]);
    const float4 s3 = *(const float4*)(&cw[3][d0]);
    float4 o;
    o.x = w0 * s0.x + w1 * s1.x + w2 * s2.x + w3 * s3.x;
    o.y = w0 * s0.y + w1 * s1.y + w2 * s2.y + w3 * s3.y;
    o.z = w0 * s0.z + w1 * s1.z + w2 * s2.z + w3 * s3.z;
    o.w = w0 * s0.w + w1 * s1.w + w2 * s2.w + w3 * s3.w;
    *(float4*)(partC + ((size_t)b * GROUPS + g) * DD + d0) = o;
    if (threadIdx.x == 0) {
        partML[((size_t)b * GROUPS + g) * 2 + 0] = M;
        partML[((size_t)b * GROUPS + g) * 2 + 1] = L;
    }
}

// ---------------- kernel 3: combine partials (float4), append x_last -------
// 64 blocks (one per batch), 256 thr, thread = 4 d's via float4.
__global__ __launch_bounds__(256) void k_final(const float* __restrict__ x,
                                               const float* __restrict__ partC,
                                               const float* __restrict__ partML,
                                               float* __restrict__ out) {
    const int b = blockIdx.x;
    __shared__ float wgt[GROUPS];
    __shared__ float lsh;

    if (threadIdx.x < GROUPS) {
        float M = -INFINITY;
        for (int cc = 0; cc < GROUPS; ++cc)
            M = fmaxf(M, partML[((size_t)b * GROUPS + cc) * 2]);
        wgt[threadIdx.x] = __expf(partML[((size_t)b * GROUPS + threadIdx.x) * 2] - M);
    }
    __syncthreads();
    if (threadIdx.x == 0) {
        float L = 0.f;
        for (int cc = 0; cc < GROUPS; ++cc)
            L += partML[((size_t)b * GROUPS + cc) * 2 + 1] * wgt[cc];
        lsh = 1.f / L;
    }
    __syncthreads();
    const float invL = lsh;

    const int d0 = threadIdx.x * 4;
    float4 acc = make_float4(0.f, 0.f, 0.f, 0.f);
#pragma unroll 8
    for (int cc = 0; cc < GROUPS; ++cc) {
        const float w = wgt[cc];
        const float4 p = *(const float4*)(partC + ((size_t)b * GROUPS + cc) * DD + d0);
        acc.x += w * p.x; acc.y += w * p.y; acc.z += w * p.z; acc.w += w * p.w;
    }
    float4 o = make_float4(acc.x * invL, acc.y * invL, acc.z * invL, acc.w * invL);
    *(float4*)(out + (size_t)b * 2048 + d0) = o;

    const float4 xl = *(const float4*)(x + ((size_t)b * TT + (TT - 1)) * DD + d0);
    *(float4*)(out + (size_t)b * 2048 + 1024 + d0) = xl;
}

extern "C" void kernel_launch(void* const* d_in, const int* in_sizes, int n_in,
                              void* d_out, int out_size, void* d_ws, size_t ws_size,
                              hipStream_t stream) {
    const float* x = (const float*)d_in[0];   // (64,512,1024) fp32
    const float* W = (const float*)d_in[1];   // (1024,1024) fp32
    float* out = (float*)d_out;               // (64,2048) fp32

    float* ws     = (float*)d_ws;             // ~8.5 MB
    float* v      = ws;                                           // 65536
    float* partC  = ws + 65536;                                   // 2097152
    float* partML = ws + 65536 + (size_t)BB * GROUPS * DD;        // 4096

    k_v<<<512, 256, 0, stream>>>(x, W, v);
    k_chunk<<<BB * GROUPS, 256, 0, stream>>>(x, v, partC, partML);
    k_final<<<BB, 256, 0, stream>>>(x, partC, partML, out);
}

// Round 20
// 39.372 us; speedup vs baseline: 1.6786x; 1.0564x over previous
//
#include <hip/hip_runtime.h>
#include <math.h>

// Problem: B=64, T=512, D=1024.
//   v[b,d]     = sum_e W[d,e] * x[b,T-1,e]
//   scores[b,t]= sum_d x[b,t,d] * v[b,d]          (t in 0..510)
//   alpha      = softmax_t(scores)
//   c[b,d]     = sum_t alpha[b,t] * x[b,t,d]
//   out[b]     = concat(c[b,:], x[b,T-1,:])       (64 x 2048 fp32)
//
// HISTORY:
//  R12 k_v 4x parallel + k_chunk lb(256,6) TLP   41.3 us  <- best
//  R13-R15 k_chunk inner variants                42.7-44.8 (inner chain exonerated)
//  R16 k_chunk x2: k_chunk+gap = 22.5us          R17 k_v x4: k_v+gap = 8.3us
//  R18 k_v diet + vec k_final                    41.6 us (neutral -> Reading B:
//      gap ~4-6us/dispatch; k_v~2, k_chunk~16.5, k_final~2; gaps ~18-20us).
//  3 dispatches is the structural minimum: v needs all of W once (redundant
//  per-block v = 27us FLOPs or 2GB W re-reads), cross-block combine needs the
//  R5-R9 fence (dead), grid.sync has the same per-block fence cost.
//  R19: shrink inter-dispatch dirty footprint: GROUPS 32->16 (partC 8->4MB).
//  Pre-commit: <=40.0 -> pursue dirty-bytes scaling; >40.5 -> declare ROOFLINE
//  (busy ~20us at BW floor + ~20us fixed dispatch overhead).

#define BB 64
#define TT 512
#define DD 1024
#define TH 511           // valid history rows: 0..510
#define GROUPS 16        // blocks per batch
#define RPW 8            // rows per wave (4 waves * 8 = 32 rows per block)

// workspace (floats):
//   v      : [BB][DD]          off 0            (65536)
//   partC  : [BB][GROUPS][DD]  off 65536        (1048576, 4 MB)
//   partML : [BB][GROUPS][2]   off 1114112      (2048)

// ---------------- kernel 1: v = x_last @ W^T -------------------------------
// 512 blocks x 4 waves; wave = 4 d-rows (W stationary) x 8 batches in pairs.
__global__ __launch_bounds__(256, 4) void k_v(const float* __restrict__ x,
                                              const float* __restrict__ W,
                                              float* __restrict__ v) {
    const int wave = threadIdx.x >> 6;
    const int lane = threadIdx.x & 63;
    const int wg   = blockIdx.x * 4 + wave;   // 0..2047
    const int d0   = (wg >> 3) * 4;           // 256 d-quads
    const int bg   = wg & 7;                  // 8 batch-groups of 8

    float4 w4[4][4];
#pragma unroll
    for (int k = 0; k < 4; ++k)
#pragma unroll
        for (int j = 0; j < 4; ++j)
            w4[k][j] = *(const float4*)(W + (size_t)(d0 + k) * DD + j * 256 + lane * 4);

    float res = 0.f;                          // lanes 0..31: (b=bg*8+(l>>2), d=d0+(l&3))
#pragma unroll
    for (int ip = 0; ip < 4; ++ip) {
        const int i0 = ip * 2;
        const float* xl0 = x + ((size_t)(bg * 8 + i0) * TT + (TT - 1)) * DD;
        const float* xl1 = xl0 + (size_t)TT * DD;
        float4 xA[4], xB[4];
#pragma unroll
        for (int j = 0; j < 4; ++j) {
            xA[j] = *(const float4*)(xl0 + j * 256 + lane * 4);
            xB[j] = *(const float4*)(xl1 + j * 256 + lane * 4);
        }
        float pA[4], pB[4];
#pragma unroll
        for (int k = 0; k < 4; ++k) {
            pA[k] = w4[k][0].x*xA[0].x + w4[k][0].y*xA[0].y + w4[k][0].z*xA[0].z + w4[k][0].w*xA[0].w
                  + w4[k][1].x*xA[1].x + w4[k][1].y*xA[1].y + w4[k][1].z*xA[1].z + w4[k][1].w*xA[1].w
                  + w4[k][2].x*xA[2].x + w4[k][2].y*xA[2].y + w4[k][2].z*xA[2].z + w4[k][2].w*xA[2].w
                  + w4[k][3].x*xA[3].x + w4[k][3].y*xA[3].y + w4[k][3].z*xA[3].z + w4[k][3].w*xA[3].w;
            pB[k] = w4[k][0].x*xB[0].x + w4[k][0].y*xB[0].y + w4[k][0].z*xB[0].z + w4[k][0].w*xB[0].w
                  + w4[k][1].x*xB[1].x + w4[k][1].y*xB[1].y + w4[k][1].z*xB[1].z + w4[k][1].w*xB[1].w
                  + w4[k][2].x*xB[2].x + w4[k][2].y*xB[2].y + w4[k][2].z*xB[2].z + w4[k][2].w*xB[2].w
                  + w4[k][3].x*xB[3].x + w4[k][3].y*xB[3].y + w4[k][3].z*xB[3].z + w4[k][3].w*xB[3].w;
        }
#pragma unroll
        for (int mm = 1; mm < 64; mm <<= 1) {  // 8 independent butterfly chains
#pragma unroll
            for (int k = 0; k < 4; ++k) {
                pA[k] += __shfl_xor(pA[k], mm, 64);
                pB[k] += __shfl_xor(pB[k], mm, 64);
            }
        }
#pragma unroll
        for (int k = 0; k < 4; ++k) {
            if (lane == i0 * 4 + k)       res = pA[k];
            if (lane == (i0 + 1) * 4 + k) res = pB[k];
        }
    }
    if (lane < 32)
        v[(size_t)(bg * 8 + (lane >> 2)) * DD + d0 + (lane & 3)] = res;
}

// ---------------- kernel 2: minimal-register flash chunk (G16, RPW=8) ------
// 1024 blocks (64 b x 16 groups), 256 thr, lb(256,6). Same proven inner loop.
__global__ __launch_bounds__(256, 6) void k_chunk(const float* __restrict__ x,
                                                  const float* __restrict__ v,
                                                  float* __restrict__ partC,
                                                  float* __restrict__ partML) {
    __shared__ float cw[4][DD];               // 16 KB combine buffer
    __shared__ float cml[4][2];

    const int b    = blockIdx.x >> 4;         // / GROUPS
    const int g    = blockIdx.x & (GROUPS - 1);
    const int wave = threadIdx.x >> 6;
    const int lane = threadIdx.x & 63;
    const int r0   = g * 32 + wave * RPW;     // <= 504
    const int col  = lane * 4;

    const float* xb = x + (size_t)b * TT * DD;
    const float* vb = v + (size_t)b * DD + col;
    const float4 vv0 = *(const float4*)(vb);
    const float4 vv1 = *(const float4*)(vb + 256);
    const float4 vv2 = *(const float4*)(vb + 512);
    const float4 vv3 = *(const float4*)(vb + 768);

    float m = -INFINITY, l = 0.f;
    float4 acc0 = make_float4(0,0,0,0), acc1 = make_float4(0,0,0,0);
    float4 acc2 = make_float4(0,0,0,0), acc3 = make_float4(0,0,0,0);

#pragma unroll
    for (int i = 0; i < RPW; ++i) {
        const int r  = r0 + i;
        const int rc = min(r, TH - 1);        // clamped addr; masked via score
        const float* p = xb + (size_t)rc * DD + col;
        const float4 x0 = *(const float4*)(p);
        const float4 x1 = *(const float4*)(p + 256);
        const float4 x2 = *(const float4*)(p + 512);
        const float4 x3 = *(const float4*)(p + 768);

        float s = vv0.x * x0.x + vv0.y * x0.y + vv0.z * x0.z + vv0.w * x0.w
                + vv1.x * x1.x + vv1.y * x1.y + vv1.z * x1.z + vv1.w * x1.w
                + vv2.x * x2.x + vv2.y * x2.y + vv2.z * x2.z + vv2.w * x2.w
                + vv3.x * x3.x + vv3.y * x3.y + vv3.z * x3.z + vv3.w * x3.w;
#pragma unroll
        for (int mm = 1; mm < 64; mm <<= 1) s += __shfl_xor(s, mm, 64);
        if (r >= TH) s = -INFINITY;           // invalid tail row -> e = 0

        const float mnew = fmaxf(m, s);
        if (mnew > m) {                        // wave-uniform branch
            const float sc = __expf(m - mnew); // first iter: exp(-inf)=0
            acc0.x *= sc; acc0.y *= sc; acc0.z *= sc; acc0.w *= sc;
            acc1.x *= sc; acc1.y *= sc; acc1.z *= sc; acc1.w *= sc;
            acc2.x *= sc; acc2.y *= sc; acc2.z *= sc; acc2.w *= sc;
            acc3.x *= sc; acc3.y *= sc; acc3.z *= sc; acc3.w *= sc;
            l *= sc; m = mnew;
        }
        const float e = __expf(s - m);
        l += e;
        acc0.x += e * x0.x; acc0.y += e * x0.y; acc0.z += e * x0.z; acc0.w += e * x0.w;
        acc1.x += e * x1.x; acc1.y += e * x1.y; acc1.z += e * x1.z; acc1.w += e * x1.w;
        acc2.x += e * x2.x; acc2.y += e * x2.y; acc2.z += e * x2.z; acc2.w += e * x2.w;
        acc3.x += e * x3.x; acc3.y += e * x3.y; acc3.z += e * x3.z; acc3.w += e * x3.w;
    }

    // one cross-wave combine per block
    *(float4*)(&cw[wave][0 * 256 + col]) = acc0;
    *(float4*)(&cw[wave][1 * 256 + col]) = acc1;
    *(float4*)(&cw[wave][2 * 256 + col]) = acc2;
    *(float4*)(&cw[wave][3 * 256 + col]) = acc3;
    if (lane == 0) { cml[wave][0] = m; cml[wave][1] = l; }
    __syncthreads();

    const float M = fmaxf(fmaxf(cml[0][0], cml[1][0]), fmaxf(cml[2][0], cml[3][0]));
    const float w0 = __expf(cml[0][0] - M), w1 = __expf(cml[1][0] - M);
    const float w2 = __expf(cml[2][0] - M), w3 = __expf(cml[3][0] - M);
    const float L = w0 * cml[0][1] + w1 * cml[1][1] + w2 * cml[2][1] + w3 * cml[3][1];

    const int d0 = threadIdx.x * 4;
    const float4 s0 = *(const float4*)(&cw[0][d0]);
    const float4 s1 = *(const float4*)(&cw[1][d0]);
    const float4 s2 = *(const float4*)(&cw[2][d0]);
    const float4 s3 = *(const float4*)(&cw[3][d0]);
    float4 o;
    o.x = w0 * s0.x + w1 * s1.x + w2 * s2.x + w3 * s3.x;
    o.y = w0 * s0.y + w1 * s1.y + w2 * s2.y + w3 * s3.y;
    o.z = w0 * s0.z + w1 * s1.z + w2 * s2.z + w3 * s3.z;
    o.w = w0 * s0.w + w1 * s1.w + w2 * s2.w + w3 * s3.w;
    *(float4*)(partC + ((size_t)b * GROUPS + g) * DD + d0) = o;
    if (threadIdx.x == 0) {
        partML[((size_t)b * GROUPS + g) * 2 + 0] = M;
        partML[((size_t)b * GROUPS + g) * 2 + 1] = L;
    }
}

// ---------------- kernel 3: combine partials (float4), append x_last -------
__global__ __launch_bounds__(256) void k_final(const float* __restrict__ x,
                                               const float* __restrict__ partC,
                                               const float* __restrict__ partML,
                                               float* __restrict__ out) {
    const int b = blockIdx.x;
    __shared__ float wgt[GROUPS];
    __shared__ float lsh;

    if (threadIdx.x < GROUPS) {
        float M = -INFINITY;
        for (int cc = 0; cc < GROUPS; ++cc)
            M = fmaxf(M, partML[((size_t)b * GROUPS + cc) * 2]);
        wgt[threadIdx.x] = __expf(partML[((size_t)b * GROUPS + threadIdx.x) * 2] - M);
    }
    __syncthreads();
    if (threadIdx.x == 0) {
        float L = 0.f;
        for (int cc = 0; cc < GROUPS; ++cc)
            L += partML[((size_t)b * GROUPS + cc) * 2 + 1] * wgt[cc];
        lsh = 1.f / L;
    }
    __syncthreads();
    const float invL = lsh;

    const int d0 = threadIdx.x * 4;
    float4 acc = make_float4(0.f, 0.f, 0.f, 0.f);
#pragma unroll
    for (int cc = 0; cc < GROUPS; ++cc) {
        const float w = wgt[cc];
        const float4 p = *(const float4*)(partC + ((size_t)b * GROUPS + cc) * DD + d0);
        acc.x += w * p.x; acc.y += w * p.y; acc.z += w * p.z; acc.w += w * p.w;
    }
    float4 o = make_float4(acc.x * invL, acc.y * invL, acc.z * invL, acc.w * invL);
    *(float4*)(out + (size_t)b * 2048 + d0) = o;

    const float4 xl = *(const float4*)(x + ((size_t)b * TT + (TT - 1)) * DD + d0);
    *(float4*)(out + (size_t)b * 2048 + 1024 + d0) = xl;
}

extern "C" void kernel_launch(void* const* d_in, const int* in_sizes, int n_in,
                              void* d_out, int out_size, void* d_ws, size_t ws_size,
                              hipStream_t stream) {
    const float* x = (const float*)d_in[0];   // (64,512,1024) fp32
    const float* W = (const float*)d_in[1];   // (1024,1024) fp32
    float* out = (float*)d_out;               // (64,2048) fp32

    float* ws     = (float*)d_ws;             // ~4.5 MB
    float* v      = ws;                                           // 65536
    float* partC  = ws + 65536;                                   // 1048576
    float* partML = ws + 65536 + (size_t)BB * GROUPS * DD;        // 2048

    k_v<<<512, 256, 0, stream>>>(x, W, v);
    k_chunk<<<BB * GROUPS, 256, 0, stream>>>(x, v, partC, partML);
    k_final<<<BB, 256, 0, stream>>>(x, partC, partML, out);
}

// Round 21
// 38.853 us; speedup vs baseline: 1.7010x; 1.0134x over previous
//
#include <hip/hip_runtime.h>
#include <hip/hip_fp16.h>
#include <math.h>

// Problem: B=64, T=512, D=1024.
//   v[b,d]     = sum_e W[d,e] * x[b,T-1,e]
//   scores[b,t]= sum_d x[b,t,d] * v[b,d]          (t in 0..510)
//   alpha      = softmax_t(scores)
//   c[b,d]     = sum_t alpha[b,t] * x[b,t,d]
//   out[b]     = concat(c[b,:], x[b,T-1,:])       (64 x 2048 fp32)
//
// HISTORY:
//  R12 best-structure baseline                   41.3 us
//  R16/R17 instrumentation: k_chunk+gap=22.5, k_v+gap=8.3 -> gaps ~5us/dispatch
//  R18 k_v diet + vec k_final                    41.6 us (k_v exonerated)
//  R19 GROUPS 32->16 (partC 8->4MB)              39.4 us (dirty-bytes lever real)
//  R20: partC in fp16 (4->2MB buffer, -4MB HBM traffic, -2MB dirty footprint).
//  partML stays fp32. If neutral -> ROOFLINE (k_chunk at ~97% stream BW;
//  3 dispatches structurally minimal; residual = fixed dispatch overhead).

#define BB 64
#define TT 512
#define DD 1024
#define TH 511           // valid history rows: 0..510
#define GROUPS 16        // blocks per batch
#define RPW 8            // rows per wave (4 waves * 8 = 32 rows per block)

// workspace:
//   v      : [BB][DD] float          off 0          (256 KB)
//   partCh : [BB][GROUPS][DD] half   off 65536 fl   (2 MB)
//   partML : [BB][GROUPS][2] float   after partCh

// ---------------- kernel 1: v = x_last @ W^T -------------------------------
// 512 blocks x 4 waves; wave = 4 d-rows (W stationary) x 8 batches in pairs.
__global__ __launch_bounds__(256, 4) void k_v(const float* __restrict__ x,
                                              const float* __restrict__ W,
                                              float* __restrict__ v) {
    const int wave = threadIdx.x >> 6;
    const int lane = threadIdx.x & 63;
    const int wg   = blockIdx.x * 4 + wave;   // 0..2047
    const int d0   = (wg >> 3) * 4;           // 256 d-quads
    const int bg   = wg & 7;                  // 8 batch-groups of 8

    float4 w4[4][4];
#pragma unroll
    for (int k = 0; k < 4; ++k)
#pragma unroll
        for (int j = 0; j < 4; ++j)
            w4[k][j] = *(const float4*)(W + (size_t)(d0 + k) * DD + j * 256 + lane * 4);

    float res = 0.f;                          // lanes 0..31: (b=bg*8+(l>>2), d=d0+(l&3))
#pragma unroll
    for (int ip = 0; ip < 4; ++ip) {
        const int i0 = ip * 2;
        const float* xl0 = x + ((size_t)(bg * 8 + i0) * TT + (TT - 1)) * DD;
        const float* xl1 = xl0 + (size_t)TT * DD;
        float4 xA[4], xB[4];
#pragma unroll
        for (int j = 0; j < 4; ++j) {
            xA[j] = *(const float4*)(xl0 + j * 256 + lane * 4);
            xB[j] = *(const float4*)(xl1 + j * 256 + lane * 4);
        }
        float pA[4], pB[4];
#pragma unroll
        for (int k = 0; k < 4; ++k) {
            pA[k] = w4[k][0].x*xA[0].x + w4[k][0].y*xA[0].y + w4[k][0].z*xA[0].z + w4[k][0].w*xA[0].w
                  + w4[k][1].x*xA[1].x + w4[k][1].y*xA[1].y + w4[k][1].z*xA[1].z + w4[k][1].w*xA[1].w
                  + w4[k][2].x*xA[2].x + w4[k][2].y*xA[2].y + w4[k][2].z*xA[2].z + w4[k][2].w*xA[2].w
                  + w4[k][3].x*xA[3].x + w4[k][3].y*xA[3].y + w4[k][3].z*xA[3].z + w4[k][3].w*xA[3].w;
            pB[k] = w4[k][0].x*xB[0].x + w4[k][0].y*xB[0].y + w4[k][0].z*xB[0].z + w4[k][0].w*xB[0].w
                  + w4[k][1].x*xB[1].x + w4[k][1].y*xB[1].y + w4[k][1].z*xB[1].z + w4[k][1].w*xB[1].w
                  + w4[k][2].x*xB[2].x + w4[k][2].y*xB[2].y + w4[k][2].z*xB[2].z + w4[k][2].w*xB[2].w
                  + w4[k][3].x*xB[3].x + w4[k][3].y*xB[3].y + w4[k][3].z*xB[3].z + w4[k][3].w*xB[3].w;
        }
#pragma unroll
        for (int mm = 1; mm < 64; mm <<= 1) {  // 8 independent butterfly chains
#pragma unroll
            for (int k = 0; k < 4; ++k) {
                pA[k] += __shfl_xor(pA[k], mm, 64);
                pB[k] += __shfl_xor(pB[k], mm, 64);
            }
        }
#pragma unroll
        for (int k = 0; k < 4; ++k) {
            if (lane == i0 * 4 + k)       res = pA[k];
            if (lane == (i0 + 1) * 4 + k) res = pB[k];
        }
    }
    if (lane < 32)
        v[(size_t)(bg * 8 + (lane >> 2)) * DD + d0 + (lane & 3)] = res;
}

// ---------------- kernel 2: minimal-register flash chunk (fp16 partials) ---
// 1024 blocks (64 b x 16 groups), 256 thr, lb(256,6). Proven inner loop.
__global__ __launch_bounds__(256, 6) void k_chunk(const float* __restrict__ x,
                                                  const float* __restrict__ v,
                                                  __half* __restrict__ partCh,
                                                  float* __restrict__ partML) {
    __shared__ float cw[4][DD];               // 16 KB combine buffer
    __shared__ float cml[4][2];

    const int b    = blockIdx.x >> 4;         // / GROUPS
    const int g    = blockIdx.x & (GROUPS - 1);
    const int wave = threadIdx.x >> 6;
    const int lane = threadIdx.x & 63;
    const int r0   = g * 32 + wave * RPW;     // <= 504
    const int col  = lane * 4;

    const float* xb = x + (size_t)b * TT * DD;
    const float* vb = v + (size_t)b * DD + col;
    const float4 vv0 = *(const float4*)(vb);
    const float4 vv1 = *(const float4*)(vb + 256);
    const float4 vv2 = *(const float4*)(vb + 512);
    const float4 vv3 = *(const float4*)(vb + 768);

    float m = -INFINITY, l = 0.f;
    float4 acc0 = make_float4(0,0,0,0), acc1 = make_float4(0,0,0,0);
    float4 acc2 = make_float4(0,0,0,0), acc3 = make_float4(0,0,0,0);

#pragma unroll
    for (int i = 0; i < RPW; ++i) {
        const int r  = r0 + i;
        const int rc = min(r, TH - 1);        // clamped addr; masked via score
        const float* p = xb + (size_t)rc * DD + col;
        const float4 x0 = *(const float4*)(p);
        const float4 x1 = *(const float4*)(p + 256);
        const float4 x2 = *(const float4*)(p + 512);
        const float4 x3 = *(const float4*)(p + 768);

        float s = vv0.x * x0.x + vv0.y * x0.y + vv0.z * x0.z + vv0.w * x0.w
                + vv1.x * x1.x + vv1.y * x1.y + vv1.z * x1.z + vv1.w * x1.w
                + vv2.x * x2.x + vv2.y * x2.y + vv2.z * x2.z + vv2.w * x2.w
                + vv3.x * x3.x + vv3.y * x3.y + vv3.z * x3.z + vv3.w * x3.w;
#pragma unroll
        for (int mm = 1; mm < 64; mm <<= 1) s += __shfl_xor(s, mm, 64);
        if (r >= TH) s = -INFINITY;           // invalid tail row -> e = 0

        const float mnew = fmaxf(m, s);
        if (mnew > m) {                        // wave-uniform branch
            const float sc = __expf(m - mnew); // first iter: exp(-inf)=0
            acc0.x *= sc; acc0.y *= sc; acc0.z *= sc; acc0.w *= sc;
            acc1.x *= sc; acc1.y *= sc; acc1.z *= sc; acc1.w *= sc;
            acc2.x *= sc; acc2.y *= sc; acc2.z *= sc; acc2.w *= sc;
            acc3.x *= sc; acc3.y *= sc; acc3.z *= sc; acc3.w *= sc;
            l *= sc; m = mnew;
        }
        const float e = __expf(s - m);
        l += e;
        acc0.x += e * x0.x; acc0.y += e * x0.y; acc0.z += e * x0.z; acc0.w += e * x0.w;
        acc1.x += e * x1.x; acc1.y += e * x1.y; acc1.z += e * x1.z; acc1.w += e * x1.w;
        acc2.x += e * x2.x; acc2.y += e * x2.y; acc2.z += e * x2.z; acc2.w += e * x2.w;
        acc3.x += e * x3.x; acc3.y += e * x3.y; acc3.z += e * x3.z; acc3.w += e * x3.w;
    }

    // one cross-wave combine per block
    *(float4*)(&cw[wave][0 * 256 + col]) = acc0;
    *(float4*)(&cw[wave][1 * 256 + col]) = acc1;
    *(float4*)(&cw[wave][2 * 256 + col]) = acc2;
    *(float4*)(&cw[wave][3 * 256 + col]) = acc3;
    if (lane == 0) { cml[wave][0] = m; cml[wave][1] = l; }
    __syncthreads();

    const float M = fmaxf(fmaxf(cml[0][0], cml[1][0]), fmaxf(cml[2][0], cml[3][0]));
    const float w0 = __expf(cml[0][0] - M), w1 = __expf(cml[1][0] - M);
    const float w2 = __expf(cml[2][0] - M), w3 = __expf(cml[3][0] - M);
    const float L = w0 * cml[0][1] + w1 * cml[1][1] + w2 * cml[2][1] + w3 * cml[3][1];

    const int d0 = threadIdx.x * 4;
    const float4 s0 = *(const float4*)(&cw[0][d0]);
    const float4 s1 = *(const float4*)(&cw[1][d0]);
    const float4 s2 = *(const float4*)(&cw[2][d0]);
    const float4 s3 = *(const float4*)(&cw[3][d0]);
    float4 o;
    o.x = w0 * s0.x + w1 * s1.x + w2 * s2.x + w3 * s3.x;
    o.y = w0 * s0.y + w1 * s1.y + w2 * s2.y + w3 * s3.y;
    o.z = w0 * s0.z + w1 * s1.z + w2 * s2.z + w3 * s3.z;
    o.w = w0 * s0.w + w1 * s1.w + w2 * s2.w + w3 * s3.w;

    // fp16 pack (values pre-division by L, O(1-100): well inside fp16 range)
    const __half2 h01 = __floats2half2_rn(o.x, o.y);
    const __half2 h23 = __floats2half2_rn(o.z, o.w);
    uint2 pk;
    pk.x = __builtin_bit_cast(unsigned int, h01);
    pk.y = __builtin_bit_cast(unsigned int, h23);
    *(uint2*)(partCh + ((size_t)b * GROUPS + g) * DD + d0) = pk;

    if (threadIdx.x == 0) {
        partML[((size_t)b * GROUPS + g) * 2 + 0] = M;
        partML[((size_t)b * GROUPS + g) * 2 + 1] = L;
    }
}

// ---------------- kernel 3: combine fp16 partials, append x_last -----------
__global__ __launch_bounds__(256) void k_final(const float* __restrict__ x,
                                               const __half* __restrict__ partCh,
                                               const float* __restrict__ partML,
                                               float* __restrict__ out) {
    const int b = blockIdx.x;
    __shared__ float wgt[GROUPS];
    __shared__ float lsh;

    if (threadIdx.x < GROUPS) {
        float M = -INFINITY;
        for (int cc = 0; cc < GROUPS; ++cc)
            M = fmaxf(M, partML[((size_t)b * GROUPS + cc) * 2]);
        wgt[threadIdx.x] = __expf(partML[((size_t)b * GROUPS + threadIdx.x) * 2] - M);
    }
    __syncthreads();
    if (threadIdx.x == 0) {
        float L = 0.f;
        for (int cc = 0; cc < GROUPS; ++cc)
            L += partML[((size_t)b * GROUPS + cc) * 2 + 1] * wgt[cc];
        lsh = 1.f / L;
    }
    __syncthreads();
    const float invL = lsh;

    const int d0 = threadIdx.x * 4;
    float4 acc = make_float4(0.f, 0.f, 0.f, 0.f);
#pragma unroll
    for (int cc = 0; cc < GROUPS; ++cc) {
        const float w = wgt[cc];
        const uint2 pk = *(const uint2*)(partCh + ((size_t)b * GROUPS + cc) * DD + d0);
        const __half2 h01 = __builtin_bit_cast(__half2, pk.x);
        const __half2 h23 = __builtin_bit_cast(__half2, pk.y);
        const float2 f01 = __half22float2(h01);
        const float2 f23 = __half22float2(h23);
        acc.x += w * f01.x; acc.y += w * f01.y;
        acc.z += w * f23.x; acc.w += w * f23.y;
    }
    float4 o = make_float4(acc.x * invL, acc.y * invL, acc.z * invL, acc.w * invL);
    *(float4*)(out + (size_t)b * 2048 + d0) = o;

    const float4 xl = *(const float4*)(x + ((size_t)b * TT + (TT - 1)) * DD + d0);
    *(float4*)(out + (size_t)b * 2048 + 1024 + d0) = xl;
}

extern "C" void kernel_launch(void* const* d_in, const int* in_sizes, int n_in,
                              void* d_out, int out_size, void* d_ws, size_t ws_size,
                              hipStream_t stream) {
    const float* x = (const float*)d_in[0];   // (64,512,1024) fp32
    const float* W = (const float*)d_in[1];   // (1024,1024) fp32
    float* out = (float*)d_out;               // (64,2048) fp32

    float*  ws     = (float*)d_ws;            // ~2.3 MB
    float*  v      = ws;                                          // 65536 floats
    __half* partCh = (__half*)(ws + 65536);                       // 1M halves (2MB)
    float*  partML = (float*)(partCh + (size_t)BB * GROUPS * DD); // 2048 floats

    k_v<<<512, 256, 0, stream>>>(x, W, v);
    k_chunk<<<BB * GROUPS, 256, 0, stream>>>(x, v, partCh, partML);
    k_final<<<BB, 256, 0, stream>>>(x, partCh, partML, out);
}